// Round 6
// baseline (101.268 us; speedup 1.0000x reference)
//
#include <hip/hip_runtime.h>

#define NH 8
#define LQ 384
#define LK 384
#define BS 2

typedef float v4f __attribute__((ext_vector_type(4)));
__device__ __forceinline__ v4f fma4(v4f a, v4f b, v4f c) { return __builtin_elementwise_fma(a, b, c); }
__device__ __forceinline__ v4f sp4(float x) { v4f r; r.x = x; r.y = x; r.z = x; r.w = x; return r; }

// ---------------- Kernel 1: Ek = exp(2*(kW+b1)), layout [bh][e4][k][4] ----------------
// grid = 384: bh = bid/24, 16-k tile. 1.5 blocks/CU.
__global__ __launch_bounds__(256) void pre_ek_kernel(
    const float* __restrict__ kin, const float* __restrict__ w1,
    const float* __restrict__ b1, float* __restrict__ ws)
{
    __shared__ float tile[16][65];
    const int bid = blockIdx.x;
    const int bh = bid / 24, kt = bid % 24;
    const int b = bh >> 3, h = bh & 7;
    const int k0 = kt * 16;
    const int tid = threadIdx.x;
    const int lane = tid & 63, w = tid >> 6;

    float w1c[32];
    const float* w1p = w1 + (size_t)(h * 64 + 32) * 64 + lane;
    #pragma unroll
    for (int d = 0; d < 32; ++d) w1c[d] = w1p[d * 64];
    const float bv = b1[h * 64 + lane];

    #pragma unroll
    for (int s = 0; s < 4; ++s) {
        int kr = w * 4 + s;
        const float* krow = kin + ((size_t)(b * LK + k0 + kr)) * (NH * 32) + h * 32;
        float acc = bv;
        #pragma unroll
        for (int d = 0; d < 32; ++d) acc = __builtin_fmaf(krow[d], w1c[d], acc);
        tile[kr][lane] = __expf(acc + acc);
    }
    __syncthreads();
    {
        int e4 = tid >> 4, k16 = tid & 15;
        float4 o;
        o.x = tile[k16][e4 * 4 + 0];
        o.y = tile[k16][e4 * 4 + 1];
        o.z = tile[k16][e4 * 4 + 2];
        o.w = tile[k16][e4 * 4 + 3];
        ((float4*)ws)[((size_t)(bh * 16 + e4)) * LK + k0 + k16] = o;
    }
}

// ---------------- Kernel 2: 6-wave (row-quad x k-third) quad-row score + deferred-norm PV ----------------
// grid = 768, block = 384 threads. wave = (pair = wave&1 row-quad, t = wave>>1 k-third of 128).
// Same per-lane score math as round-3 (8-way rcp merge); occupancy 12 -> 18 waves/CU for
// latency hiding (kernel was TLP-limited: 3 waves/SIMD).
__global__ __launch_bounds__(384, 5) void attn_kernel(
    const float* __restrict__ qin, const float* __restrict__ vin,
    const int* __restrict__ qlens, const int* __restrict__ klens,
    const float* __restrict__ w1, const float* __restrict__ w2g,
    const float* __restrict__ ws,
    float* __restrict__ outg, float* __restrict__ attg)
{
    __shared__ __align__(16) float eqi_s[2][256];      // [row-quad][e*4+row] interleaved Eq
    __shared__ __align__(16) float att_h[6][4 * 128];  // [wave][row*128 + k] wave-private e_
    __shared__ __align__(16) float w2s[64];
    __shared__ float2 smu[2][4][3];                    // [row-quad][row][third] (max, sum)
    __shared__ __align__(16) float4 pvp[2][3][4][8];   // [row-quad][third][row][dvq]

    const int tid = threadIdx.x, wave = tid >> 6, lane = tid & 63;
    const int pair = wave & 1, t = wave >> 1;          // row-quad, k-third
    const int bh = blockIdx.x / 48, tile = blockIdx.x % 48;
    const int b = bh >> 3, h = bh & 7;
    const int q0 = tile * 8;
    const int klen = klens[b], qlen = qlens[b];

    // ---- Eq: waves 0..3 compute rows 2w, 2w+1 (e = lane); wave 4 stages w2 ----
    if (wave < 4) {
        float w1c[32];
        const float* w1p = w1 + (size_t)h * 64 * 64 + lane;
        #pragma unroll
        for (int d = 0; d < 32; ++d) w1c[d] = w1p[d * 64];
        #pragma unroll
        for (int j = 0; j < 2; ++j) {
            int r = wave * 2 + j;
            const float* qp = qin + ((size_t)(b * LQ + q0 + r)) * (NH * 32) + h * 32;
            float a = 0.f;
            #pragma unroll
            for (int d = 0; d < 32; ++d) a = __builtin_fmaf(qp[d], w1c[d], a);
            eqi_s[r >> 2][lane * 4 + (r & 3)] = __expf(a + a);
        }
    } else if (wave == 4) {
        w2s[lane] = w2g[h * 64 + lane];
    }
    __syncthreads();   // (1)

    // ---- score: k = t*128 + c*64 + lane; 4 q-rows per lane; e4 pairs share one rcp ----
    v4f sc[2];
    sc[0] = sp4(0.f); sc[1] = sp4(0.f);
    const float4* ekq = (const float4*)ws + ((size_t)bh * 16) * LK + t * 128 + lane;
    const v4f*   eqp = (const v4f*)eqi_s[pair];
    const float4* w2p = (const float4*)w2s;

    float4 kva[2], kvb[2];
    #pragma unroll
    for (int c = 0; c < 2; ++c) kva[c] = ekq[c * 64];
    #pragma unroll
    for (int c = 0; c < 2; ++c) kvb[c] = ekq[LK + c * 64];

    #pragma unroll
    for (int p = 0; p < 8; ++p) {
        const int ea = 2 * p, eb = 2 * p + 1;
        float4 As[2] = {kva[0], kva[1]};
        float4 Bs[2] = {kvb[0], kvb[1]};
        if (p < 7) {
            const float4* np = ekq + (size_t)(ea + 2) * LK;
            kva[0] = np[0]; kva[1] = np[64];
            const float4* nq = ekq + (size_t)(eb + 2) * LK;
            kvb[0] = nq[0]; kvb[1] = nq[64];
        }
        v4f Ea0 = eqp[ea * 4 + 0];
        v4f Ea1 = eqp[ea * 4 + 1];
        v4f Ea2 = eqp[ea * 4 + 2];
        v4f Ea3 = eqp[ea * 4 + 3];
        v4f Eb0 = eqp[eb * 4 + 0];
        v4f Eb1 = eqp[eb * 4 + 1];
        v4f Eb2 = eqp[eb * 4 + 2];
        v4f Eb3 = eqp[eb * 4 + 3];
        float4 wva = w2p[ea], wvb = w2p[eb];
        #pragma unroll
        for (int c = 0; c < 2; ++c) {
            float4 ka = As[c], kb = Bs[c];
            // quad A (e = 4*ea .. 4*ea+3)
            v4f ta0 = fma4(Ea0, sp4(ka.x), sp4(1.f));
            v4f ta1 = fma4(Ea1, sp4(ka.y), sp4(1.f));
            v4f ta2 = fma4(Ea2, sp4(ka.z), sp4(1.f));
            v4f ta3 = fma4(Ea3, sp4(ka.w), sp4(1.f));
            v4f pa12 = ta0 * ta1, pa34 = ta2 * ta3;
            v4f na12 = fma4(sp4(wva.y), ta0, sp4(wva.x) * ta1);
            v4f na34 = fma4(sp4(wva.w), ta2, sp4(wva.z) * ta3);
            v4f numA = fma4(na34, pa12, na12 * pa34);
            v4f denA = pa12 * pa34;
            // quad B (e = 4*eb .. 4*eb+3)
            v4f tb0 = fma4(Eb0, sp4(kb.x), sp4(1.f));
            v4f tb1 = fma4(Eb1, sp4(kb.y), sp4(1.f));
            v4f tb2 = fma4(Eb2, sp4(kb.z), sp4(1.f));
            v4f tb3 = fma4(Eb3, sp4(kb.w), sp4(1.f));
            v4f pb12 = tb0 * tb1, pb34 = tb2 * tb3;
            v4f nb12 = fma4(sp4(wvb.y), tb0, sp4(wvb.x) * tb1);
            v4f nb34 = fma4(sp4(wvb.w), tb2, sp4(wvb.z) * tb3);
            v4f numB = fma4(nb34, pb12, nb12 * pb34);
            v4f denB = pb12 * pb34;
            // merge: numA/denA + numB/denB = (numA*denB + numB*denA) / (denA*denB)
            v4f num = fma4(numB, denA, numA * denB);
            v4f den = denA * denB;
            v4f r;
            r.x = __builtin_amdgcn_rcpf(den.x);
            r.y = __builtin_amdgcn_rcpf(den.y);
            r.z = __builtin_amdgcn_rcpf(den.z);
            r.w = __builtin_amdgcn_rcpf(den.w);
            sc[c] = fma4(num, r, sc[c]);
        }
    }

    // ---- wave-local softmax stats (4 rows, 128 k per wave) ----
    float s_[2][4];
    float m_[4] = {-3.4e38f, -3.4e38f, -3.4e38f, -3.4e38f};
    #pragma unroll
    for (int c = 0; c < 2; ++c) {
        int kk = t * 128 + c * 64 + lane;
        bool ok = kk < klen;
        #pragma unroll
        for (int r = 0; r < 4; ++r) {
            s_[c][r] = ok ? -2.0f * sc[c][r] : -3.4e38f;
            m_[r] = fmaxf(m_[r], s_[c][r]);
        }
    }
    #pragma unroll
    for (int off = 32; off >= 1; off >>= 1) {
        #pragma unroll
        for (int r = 0; r < 4; ++r) m_[r] = fmaxf(m_[r], __shfl_xor(m_[r], off));
    }
    float e_[2][4];
    float u_[4] = {0.f, 0.f, 0.f, 0.f};
    #pragma unroll
    for (int c = 0; c < 2; ++c) {
        int kk = t * 128 + c * 64 + lane;
        bool ok = kk < klen;
        #pragma unroll
        for (int r = 0; r < 4; ++r) {
            e_[c][r] = ok ? __expf(s_[c][r] - m_[r]) : 0.f;
            u_[r] += e_[c][r];
        }
    }
    #pragma unroll
    for (int off = 32; off >= 1; off >>= 1) {
        #pragma unroll
        for (int r = 0; r < 4; ++r) u_[r] += __shfl_xor(u_[r], off);
    }
    if (lane == 0) {
        #pragma unroll
        for (int r = 0; r < 4; ++r) smu[pair][r][t] = make_float2(m_[r], u_[r]);
    }
    // e_ -> wave-private LDS (same-wave RAW, no barrier)
    {
        float* ar = att_h[wave];
        #pragma unroll
        for (int c = 0; c < 2; ++c)
            #pragma unroll
            for (int r = 0; r < 4; ++r)
                ar[r * 128 + c * 64 + lane] = e_[c][r];
    }

    // ---- PV with UNNORMALIZED e_ weights over this wave's 128 k ----
    const int kf = lane >> 3, dg = lane & 7;
    const float* vbase = vin + (size_t)b * LK * (NH * 32) + h * 32
                       + (size_t)(t * 128 + kf) * (NH * 32) + dg * 4;
    const float* ap = att_h[wave];
    float oa[4][4] = {{0.f,0.f,0.f,0.f},{0.f,0.f,0.f,0.f},{0.f,0.f,0.f,0.f},{0.f,0.f,0.f,0.f}};
    float4 vbuf[2];
    vbuf[0] = *(const float4*)(vbase);
    vbuf[1] = *(const float4*)(vbase + (size_t)8 * (NH * 32));
    #pragma unroll
    for (int i = 0; i < 16; ++i) {
        float4 vv = vbuf[i & 1];
        if (i < 14) vbuf[i & 1] = *(const float4*)(vbase + (size_t)((i + 2) * 8) * (NH * 32));
        int k0 = i * 8;
        #pragma unroll
        for (int r = 0; r < 4; ++r) {
            float a = ap[r * 128 + k0 + kf];
            oa[r][0] = __builtin_fmaf(a, vv.x, oa[r][0]);
            oa[r][1] = __builtin_fmaf(a, vv.y, oa[r][1]);
            oa[r][2] = __builtin_fmaf(a, vv.z, oa[r][2]);
            oa[r][3] = __builtin_fmaf(a, vv.w, oa[r][3]);
        }
    }
    #pragma unroll
    for (int r = 0; r < 4; ++r)
        #pragma unroll
        for (int u = 0; u < 4; ++u) {
            oa[r][u] += __shfl_xor(oa[r][u], 8);
            oa[r][u] += __shfl_xor(oa[r][u], 16);
            oa[r][u] += __shfl_xor(oa[r][u], 32);
        }
    __syncthreads();   // (2) smu written long ago by all waves; near-free sync

    // ---- normalization factors (3-way cross-third merge), per row ----
    float f_[4];
    #pragma unroll
    for (int r = 0; r < 4; ++r) {
        float2 A = smu[pair][r][0], B = smu[pair][r][1], C = smu[pair][r][2];
        float mm = fmaxf(fmaxf(A.x, B.x), C.x);
        float uu = A.y * __expf(A.x - mm) + B.y * __expf(B.x - mm) + C.y * __expf(C.x - mm);
        f_[r] = __expf(m_[r] - mm) * __builtin_amdgcn_rcpf(uu);
    }

    if (kf == 0) {   // lanes 0..7: scale reduced partials by this wave's factor
        #pragma unroll
        for (int r = 0; r < 4; ++r)
            pvp[pair][t][r][dg] = make_float4(oa[r][0] * f_[r], oa[r][1] * f_[r],
                                              oa[r][2] * f_[r], oa[r][3] * f_[r]);
    }

    // ---- att global writes: p = e_ * f (coalesced, this wave's k-third) ----
    {
        float* ag = attg + ((size_t)(bh * LQ + q0 + pair * 4)) * LK + t * 128;
        #pragma unroll
        for (int r = 0; r < 4; ++r) {
            #pragma unroll
            for (int c = 0; c < 2; ++c) ag[c * 64 + lane] = e_[c][r] * f_[r];
            ag += LK;
        }
    }
    __syncthreads();   // (3)

    // ---- combine PV thirds: wave 0, lane = r*8 + dg ----
    if (wave == 0) {
        int r = lane >> 3, dgo = lane & 7;
        int pr = r >> 2, rr = r & 3;
        float4 x0 = pvp[pr][0][rr][dgo], x1 = pvp[pr][1][rr][dgo], x2 = pvp[pr][2][rr][dgo];
        int q = q0 + r;
        bool okq = (q < qlen);
        float4 o4;
        o4.x = okq ? (x0.x + x1.x + x2.x) : 0.f;
        o4.y = okq ? (x0.y + x1.y + x2.y) : 0.f;
        o4.z = okq ? (x0.z + x1.z + x2.z) : 0.f;
        o4.w = okq ? (x0.w + x1.w + x2.w) : 0.f;
        ((float4*)(outg + ((size_t)(b * LQ + q)) * (NH * 32) + h * 32))[dgo] = o4;
    }
}

extern "C" void kernel_launch(void* const* d_in, const int* in_sizes, int n_in,
                              void* d_out, int out_size, void* d_ws, size_t ws_size,
                              hipStream_t stream) {
    const float* q    = (const float*)d_in[0];
    const float* k    = (const float*)d_in[1];
    const float* v    = (const float*)d_in[2];
    const int*   qlen = (const int*)d_in[3];
    const int*   klen = (const int*)d_in[4];
    const float* w1   = (const float*)d_in[5];
    const float* b1   = (const float*)d_in[6];
    const float* w2   = (const float*)d_in[7];
    float* out = (float*)d_out;
    float* att = out + (size_t)BS * LQ * NH * 32;   // out: 196608, att: 2359296 floats
    float* ws  = (float*)d_ws;                      // Ek [bh][e4][k][4]: 1.5 MB

    pre_ek_kernel<<<384, 256, 0, stream>>>(k, w1, b1, ws);
    attn_kernel<<<768, 384, 0, stream>>>(q, v, qlen, klen, w1, w2, ws, out, att);
}

// Round 7
// 99.506 us; speedup vs baseline: 1.0177x; 1.0177x over previous
//
#include <hip/hip_runtime.h>

#define NH 8
#define LQ 384
#define LK 384
#define BS 2

typedef float v4f __attribute__((ext_vector_type(4)));
__device__ __forceinline__ v4f fma4(v4f a, v4f b, v4f c) { return __builtin_elementwise_fma(a, b, c); }
__device__ __forceinline__ v4f sp4(float x) { v4f r; r.x = x; r.y = x; r.z = x; r.w = x; return r; }

// ---------------- Kernel 1: Ek = exp(2*(kW+b1)), layout [bh][e4][k][4] ----------------
// grid = 384: bh = bid/24, 16-k tile. 1.5 blocks/CU.
__global__ __launch_bounds__(256) void pre_ek_kernel(
    const float* __restrict__ kin, const float* __restrict__ w1,
    const float* __restrict__ b1, float* __restrict__ ws)
{
    __shared__ float tile[16][65];
    const int bid = blockIdx.x;
    const int bh = bid / 24, kt = bid % 24;
    const int b = bh >> 3, h = bh & 7;
    const int k0 = kt * 16;
    const int tid = threadIdx.x;
    const int lane = tid & 63, w = tid >> 6;

    float w1c[32];
    const float* w1p = w1 + (size_t)(h * 64 + 32) * 64 + lane;
    #pragma unroll
    for (int d = 0; d < 32; ++d) w1c[d] = w1p[d * 64];
    const float bv = b1[h * 64 + lane];

    #pragma unroll
    for (int s = 0; s < 4; ++s) {
        int kr = w * 4 + s;
        const float* krow = kin + ((size_t)(b * LK + k0 + kr)) * (NH * 32) + h * 32;
        float acc = bv;
        #pragma unroll
        for (int d = 0; d < 32; ++d) acc = __builtin_fmaf(krow[d], w1c[d], acc);
        tile[kr][lane] = __expf(acc + acc);
    }
    __syncthreads();
    {
        int e4 = tid >> 4, k16 = tid & 15;
        float4 o;
        o.x = tile[k16][e4 * 4 + 0];
        o.y = tile[k16][e4 * 4 + 1];
        o.z = tile[k16][e4 * 4 + 2];
        o.w = tile[k16][e4 * 4 + 3];
        ((float4*)ws)[((size_t)(bh * 16 + e4)) * LK + k0 + k16] = o;
    }
}

// ---------------- Kernel 2: 6-wave (row-quad x k-third) quad-row score + deferred-norm PV ----------------
// grid = 768, block = 384 threads. wave = (pair = wave&1 row-quad, t = wave>>1 k-third of 128).
// Same per-lane score math as round-3 (8-way rcp merge); occupancy 12 -> 18 waves/CU.
// launch_bounds(384,3): cap ~170 VGPR -- round-6's (384,5) forced VGPR=48 and spilled
// to scratch (cold 133us, VALUBusy 2.7%). 3 blocks/CU is grid-limited anyway.
__global__ __launch_bounds__(384, 3) void attn_kernel(
    const float* __restrict__ qin, const float* __restrict__ vin,
    const int* __restrict__ qlens, const int* __restrict__ klens,
    const float* __restrict__ w1, const float* __restrict__ w2g,
    const float* __restrict__ ws,
    float* __restrict__ outg, float* __restrict__ attg)
{
    __shared__ __align__(16) float eqi_s[2][256];      // [row-quad][e*4+row] interleaved Eq
    __shared__ __align__(16) float att_h[6][4 * 128];  // [wave][row*128 + k] wave-private e_
    __shared__ __align__(16) float w2s[64];
    __shared__ float2 smu[2][4][3];                    // [row-quad][row][third] (max, sum)
    __shared__ __align__(16) float4 pvp[2][3][4][8];   // [row-quad][third][row][dvq]

    const int tid = threadIdx.x, wave = tid >> 6, lane = tid & 63;
    const int pair = wave & 1, t = wave >> 1;          // row-quad, k-third
    const int bh = blockIdx.x / 48, tile = blockIdx.x % 48;
    const int b = bh >> 3, h = bh & 7;
    const int q0 = tile * 8;
    const int klen = klens[b], qlen = qlens[b];

    // ---- Eq: waves 0..3 compute rows 2w, 2w+1 (e = lane); wave 4 stages w2 ----
    if (wave < 4) {
        float w1c[32];
        const float* w1p = w1 + (size_t)h * 64 * 64 + lane;
        #pragma unroll
        for (int d = 0; d < 32; ++d) w1c[d] = w1p[d * 64];
        #pragma unroll
        for (int j = 0; j < 2; ++j) {
            int r = wave * 2 + j;
            const float* qp = qin + ((size_t)(b * LQ + q0 + r)) * (NH * 32) + h * 32;
            float a = 0.f;
            #pragma unroll
            for (int d = 0; d < 32; ++d) a = __builtin_fmaf(qp[d], w1c[d], a);
            eqi_s[r >> 2][lane * 4 + (r & 3)] = __expf(a + a);
        }
    } else if (wave == 4) {
        w2s[lane] = w2g[h * 64 + lane];
    }
    __syncthreads();   // (1)

    // ---- score: k = t*128 + c*64 + lane; 4 q-rows per lane; e4 pairs share one rcp ----
    v4f sc[2];
    sc[0] = sp4(0.f); sc[1] = sp4(0.f);
    const float4* ekq = (const float4*)ws + ((size_t)bh * 16) * LK + t * 128 + lane;
    const v4f*   eqp = (const v4f*)eqi_s[pair];
    const float4* w2p = (const float4*)w2s;

    float4 kva[2], kvb[2];
    #pragma unroll
    for (int c = 0; c < 2; ++c) kva[c] = ekq[c * 64];
    #pragma unroll
    for (int c = 0; c < 2; ++c) kvb[c] = ekq[LK + c * 64];

    #pragma unroll
    for (int p = 0; p < 8; ++p) {
        const int ea = 2 * p, eb = 2 * p + 1;
        float4 As[2] = {kva[0], kva[1]};
        float4 Bs[2] = {kvb[0], kvb[1]};
        if (p < 7) {
            const float4* np = ekq + (size_t)(ea + 2) * LK;
            kva[0] = np[0]; kva[1] = np[64];
            const float4* nq = ekq + (size_t)(eb + 2) * LK;
            kvb[0] = nq[0]; kvb[1] = nq[64];
        }
        v4f Ea0 = eqp[ea * 4 + 0];
        v4f Ea1 = eqp[ea * 4 + 1];
        v4f Ea2 = eqp[ea * 4 + 2];
        v4f Ea3 = eqp[ea * 4 + 3];
        v4f Eb0 = eqp[eb * 4 + 0];
        v4f Eb1 = eqp[eb * 4 + 1];
        v4f Eb2 = eqp[eb * 4 + 2];
        v4f Eb3 = eqp[eb * 4 + 3];
        float4 wva = w2p[ea], wvb = w2p[eb];
        #pragma unroll
        for (int c = 0; c < 2; ++c) {
            float4 ka = As[c], kb = Bs[c];
            // quad A (e = 4*ea .. 4*ea+3)
            v4f ta0 = fma4(Ea0, sp4(ka.x), sp4(1.f));
            v4f ta1 = fma4(Ea1, sp4(ka.y), sp4(1.f));
            v4f ta2 = fma4(Ea2, sp4(ka.z), sp4(1.f));
            v4f ta3 = fma4(Ea3, sp4(ka.w), sp4(1.f));
            v4f pa12 = ta0 * ta1, pa34 = ta2 * ta3;
            v4f na12 = fma4(sp4(wva.y), ta0, sp4(wva.x) * ta1);
            v4f na34 = fma4(sp4(wva.w), ta2, sp4(wva.z) * ta3);
            v4f numA = fma4(na34, pa12, na12 * pa34);
            v4f denA = pa12 * pa34;
            // quad B (e = 4*eb .. 4*eb+3)
            v4f tb0 = fma4(Eb0, sp4(kb.x), sp4(1.f));
            v4f tb1 = fma4(Eb1, sp4(kb.y), sp4(1.f));
            v4f tb2 = fma4(Eb2, sp4(kb.z), sp4(1.f));
            v4f tb3 = fma4(Eb3, sp4(kb.w), sp4(1.f));
            v4f pb12 = tb0 * tb1, pb34 = tb2 * tb3;
            v4f nb12 = fma4(sp4(wvb.y), tb0, sp4(wvb.x) * tb1);
            v4f nb34 = fma4(sp4(wvb.w), tb2, sp4(wvb.z) * tb3);
            v4f numB = fma4(nb34, pb12, nb12 * pb34);
            v4f denB = pb12 * pb34;
            // merge: numA/denA + numB/denB = (numA*denB + numB*denA) / (denA*denB)
            v4f num = fma4(numB, denA, numA * denB);
            v4f den = denA * denB;
            v4f r;
            r.x = __builtin_amdgcn_rcpf(den.x);
            r.y = __builtin_amdgcn_rcpf(den.y);
            r.z = __builtin_amdgcn_rcpf(den.z);
            r.w = __builtin_amdgcn_rcpf(den.w);
            sc[c] = fma4(num, r, sc[c]);
        }
    }

    // ---- wave-local softmax stats (4 rows, 128 k per wave) ----
    float s_[2][4];
    float m_[4] = {-3.4e38f, -3.4e38f, -3.4e38f, -3.4e38f};
    #pragma unroll
    for (int c = 0; c < 2; ++c) {
        int kk = t * 128 + c * 64 + lane;
        bool ok = kk < klen;
        #pragma unroll
        for (int r = 0; r < 4; ++r) {
            s_[c][r] = ok ? -2.0f * sc[c][r] : -3.4e38f;
            m_[r] = fmaxf(m_[r], s_[c][r]);
        }
    }
    #pragma unroll
    for (int off = 32; off >= 1; off >>= 1) {
        #pragma unroll
        for (int r = 0; r < 4; ++r) m_[r] = fmaxf(m_[r], __shfl_xor(m_[r], off));
    }
    float e_[2][4];
    float u_[4] = {0.f, 0.f, 0.f, 0.f};
    #pragma unroll
    for (int c = 0; c < 2; ++c) {
        int kk = t * 128 + c * 64 + lane;
        bool ok = kk < klen;
        #pragma unroll
        for (int r = 0; r < 4; ++r) {
            e_[c][r] = ok ? __expf(s_[c][r] - m_[r]) : 0.f;
            u_[r] += e_[c][r];
        }
    }
    #pragma unroll
    for (int off = 32; off >= 1; off >>= 1) {
        #pragma unroll
        for (int r = 0; r < 4; ++r) u_[r] += __shfl_xor(u_[r], off);
    }
    if (lane == 0) {
        #pragma unroll
        for (int r = 0; r < 4; ++r) smu[pair][r][t] = make_float2(m_[r], u_[r]);
    }
    // e_ -> wave-private LDS (same-wave RAW, no barrier)
    {
        float* ar = att_h[wave];
        #pragma unroll
        for (int c = 0; c < 2; ++c)
            #pragma unroll
            for (int r = 0; r < 4; ++r)
                ar[r * 128 + c * 64 + lane] = e_[c][r];
    }

    // ---- PV with UNNORMALIZED e_ weights over this wave's 128 k ----
    const int kf = lane >> 3, dg = lane & 7;
    const float* vbase = vin + (size_t)b * LK * (NH * 32) + h * 32
                       + (size_t)(t * 128 + kf) * (NH * 32) + dg * 4;
    const float* ap = att_h[wave];
    float oa[4][4] = {{0.f,0.f,0.f,0.f},{0.f,0.f,0.f,0.f},{0.f,0.f,0.f,0.f},{0.f,0.f,0.f,0.f}};
    float4 vbuf[2];
    vbuf[0] = *(const float4*)(vbase);
    vbuf[1] = *(const float4*)(vbase + (size_t)8 * (NH * 32));
    #pragma unroll
    for (int i = 0; i < 16; ++i) {
        float4 vv = vbuf[i & 1];
        if (i < 14) vbuf[i & 1] = *(const float4*)(vbase + (size_t)((i + 2) * 8) * (NH * 32));
        int k0 = i * 8;
        #pragma unroll
        for (int r = 0; r < 4; ++r) {
            float a = ap[r * 128 + k0 + kf];
            oa[r][0] = __builtin_fmaf(a, vv.x, oa[r][0]);
            oa[r][1] = __builtin_fmaf(a, vv.y, oa[r][1]);
            oa[r][2] = __builtin_fmaf(a, vv.z, oa[r][2]);
            oa[r][3] = __builtin_fmaf(a, vv.w, oa[r][3]);
        }
    }
    #pragma unroll
    for (int r = 0; r < 4; ++r)
        #pragma unroll
        for (int u = 0; u < 4; ++u) {
            oa[r][u] += __shfl_xor(oa[r][u], 8);
            oa[r][u] += __shfl_xor(oa[r][u], 16);
            oa[r][u] += __shfl_xor(oa[r][u], 32);
        }
    __syncthreads();   // (2) smu written long ago by all waves; near-free sync

    // ---- normalization factors (3-way cross-third merge), per row ----
    float f_[4];
    #pragma unroll
    for (int r = 0; r < 4; ++r) {
        float2 A = smu[pair][r][0], B = smu[pair][r][1], C = smu[pair][r][2];
        float mm = fmaxf(fmaxf(A.x, B.x), C.x);
        float uu = A.y * __expf(A.x - mm) + B.y * __expf(B.x - mm) + C.y * __expf(C.x - mm);
        f_[r] = __expf(m_[r] - mm) * __builtin_amdgcn_rcpf(uu);
    }

    if (kf == 0) {   // lanes 0..7: scale reduced partials by this wave's factor
        #pragma unroll
        for (int r = 0; r < 4; ++r)
            pvp[pair][t][r][dg] = make_float4(oa[r][0] * f_[r], oa[r][1] * f_[r],
                                              oa[r][2] * f_[r], oa[r][3] * f_[r]);
    }

    // ---- att global writes: p = e_ * f (coalesced, this wave's k-third) ----
    {
        float* ag = attg + ((size_t)(bh * LQ + q0 + pair * 4)) * LK + t * 128;
        #pragma unroll
        for (int r = 0; r < 4; ++r) {
            #pragma unroll
            for (int c = 0; c < 2; ++c) ag[c * 64 + lane] = e_[c][r] * f_[r];
            ag += LK;
        }
    }
    __syncthreads();   // (3)

    // ---- combine PV thirds: wave 0, lane = r*8 + dg ----
    if (wave == 0) {
        int r = lane >> 3, dgo = lane & 7;
        int pr = r >> 2, rr = r & 3;
        float4 x0 = pvp[pr][0][rr][dgo], x1 = pvp[pr][1][rr][dgo], x2 = pvp[pr][2][rr][dgo];
        int q = q0 + r;
        bool okq = (q < qlen);
        float4 o4;
        o4.x = okq ? (x0.x + x1.x + x2.x) : 0.f;
        o4.y = okq ? (x0.y + x1.y + x2.y) : 0.f;
        o4.z = okq ? (x0.z + x1.z + x2.z) : 0.f;
        o4.w = okq ? (x0.w + x1.w + x2.w) : 0.f;
        ((float4*)(outg + ((size_t)(b * LQ + q)) * (NH * 32) + h * 32))[dgo] = o4;
    }
}

extern "C" void kernel_launch(void* const* d_in, const int* in_sizes, int n_in,
                              void* d_out, int out_size, void* d_ws, size_t ws_size,
                              hipStream_t stream) {
    const float* q    = (const float*)d_in[0];
    const float* k    = (const float*)d_in[1];
    const float* v    = (const float*)d_in[2];
    const int*   qlen = (const int*)d_in[3];
    const int*   klen = (const int*)d_in[4];
    const float* w1   = (const float*)d_in[5];
    const float* b1   = (const float*)d_in[6];
    const float* w2   = (const float*)d_in[7];
    float* out = (float*)d_out;
    float* att = out + (size_t)BS * LQ * NH * 32;   // out: 196608, att: 2359296 floats
    float* ws  = (float*)d_ws;                      // Ek [bh][e4][k][4]: 1.5 MB

    pre_ek_kernel<<<384, 256, 0, stream>>>(k, w1, b1, ws);
    attn_kernel<<<768, 384, 0, stream>>>(q, v, qlen, klen, w1, w2, ws, out, att);
}

// Round 8
// 94.159 us; speedup vs baseline: 1.0755x; 1.0568x over previous
//
#include <hip/hip_runtime.h>

#define NH 8
#define LQ 384
#define LK 384
#define BS 2

typedef float v4f __attribute__((ext_vector_type(4)));
__device__ __forceinline__ v4f fma4(v4f a, v4f b, v4f c) { return __builtin_elementwise_fma(a, b, c); }
__device__ __forceinline__ v4f sp4(float x) { v4f r; r.x = x; r.y = x; r.z = x; r.w = x; return r; }

// ---------------- Kernel 1: Ek = exp(2*(kW+b1)), layout [bh][e4][k][4] ----------------
// grid = 768: bh = bid/48, 8-k tile. 3 blocks/CU, 12 waves/CU (was 384 blocks = 1.5/CU:
// latency-bound, half the CUs ran 2 blocks serially). Per-output math bit-identical.
__global__ __launch_bounds__(256) void pre_ek_kernel(
    const float* __restrict__ kin, const float* __restrict__ w1,
    const float* __restrict__ b1, float* __restrict__ ws)
{
    __shared__ float tile[8][65];
    const int bid = blockIdx.x;
    const int bh = bid / 48, kt = bid % 48;
    const int b = bh >> 3, h = bh & 7;
    const int k0 = kt * 8;
    const int tid = threadIdx.x;
    const int lane = tid & 63, w = tid >> 6;

    float w1c[32];
    const float* w1p = w1 + (size_t)(h * 64 + 32) * 64 + lane;
    #pragma unroll
    for (int d = 0; d < 32; ++d) w1c[d] = w1p[d * 64];
    const float bv = b1[h * 64 + lane];

    #pragma unroll
    for (int s = 0; s < 2; ++s) {
        int kr = w * 2 + s;
        const float* krow = kin + ((size_t)(b * LK + k0 + kr)) * (NH * 32) + h * 32;
        float acc = bv;
        #pragma unroll
        for (int d = 0; d < 32; ++d) acc = __builtin_fmaf(krow[d], w1c[d], acc);
        tile[kr][lane] = __expf(acc + acc);
    }
    __syncthreads();
    if (tid < 128) {
        int e4 = tid >> 3, k8 = tid & 7;
        float4 o;
        o.x = tile[k8][e4 * 4 + 0];
        o.y = tile[k8][e4 * 4 + 1];
        o.z = tile[k8][e4 * 4 + 2];
        o.w = tile[k8][e4 * 4 + 3];
        ((float4*)ws)[((size_t)(bh * 16 + e4)) * LK + k0 + k8] = o;
    }
}

// ---------------- Kernel 2: quad-row (v4f) score + paired-rcp + deferred-normalization PV ----------------
// grid = 768 (3 blocks/CU): bh = blk/48, q-tile of 8; wave=(pair4, k-half), 4 q-rows per lane.
// Score inner loop merges rcp across e4-quad PAIRS: 8 e-terms share one v_rcp per row.
// [round-3 structure, proven 93.74 us. r2/r4/r5/r6-7 ablations: 8-row packing (VGPR blowup),
//  16-way rcp (+1.8), V-LDS staging (+2.6, warm-L2 regime), 384-thr TLP (VGPR cap bug) all hurt.]
__global__ __launch_bounds__(256) void attn_kernel(
    const float* __restrict__ qin, const float* __restrict__ vin,
    const int* __restrict__ qlens, const int* __restrict__ klens,
    const float* __restrict__ w1, const float* __restrict__ w2g,
    const float* __restrict__ ws,
    float* __restrict__ outg, float* __restrict__ attg)
{
    __shared__ __align__(16) float eqi_s[2][256];      // [pair4][e*4+row] interleaved Eq
    __shared__ __align__(16) float att_h[4][4 * 192];  // [wave][row*192 + k] wave-private e_
    __shared__ __align__(16) float w2s[64];
    __shared__ float2 smu[2][4][2];                    // [pair4][row][half] (max, sum)
    __shared__ __align__(16) float4 pvp[2][2][4][8];   // [pair4][half][row][dvq]

    const int tid = threadIdx.x, wave = tid >> 6, lane = tid & 63;
    const int pair = wave >> 1, hh = wave & 1;
    const int bh = blockIdx.x / 48, tile = blockIdx.x % 48;
    const int b = bh >> 3, h = bh & 7;
    const int q0 = tile * 8;
    const int klen = klens[b], qlen = qlens[b];

    // ---- Eq: wave w computes rows 2w, 2w+1 (e = lane), interleaved 4-row groups ----
    {
        float w1c[32];
        const float* w1p = w1 + (size_t)h * 64 * 64 + lane;
        #pragma unroll
        for (int d = 0; d < 32; ++d) w1c[d] = w1p[d * 64];
        #pragma unroll
        for (int j = 0; j < 2; ++j) {
            int r = wave * 2 + j;
            const float* qp = qin + ((size_t)(b * LQ + q0 + r)) * (NH * 32) + h * 32;
            float a = 0.f;
            #pragma unroll
            for (int d = 0; d < 32; ++d) a = __builtin_fmaf(qp[d], w1c[d], a);
            eqi_s[r >> 2][lane * 4 + (r & 3)] = __expf(a + a);
        }
        if (wave == 0) w2s[lane] = w2g[h * 64 + lane];
    }
    __syncthreads();   // (1)

    // ---- score: k = hh*192 + c*64 + lane; 4 q-rows per lane; e4 pairs share one rcp ----
    v4f sc[3];
    sc[0] = sp4(0.f); sc[1] = sp4(0.f); sc[2] = sp4(0.f);
    const float4* ekq = (const float4*)ws + ((size_t)bh * 16) * LK + hh * 192 + lane;
    const v4f*   eqp = (const v4f*)eqi_s[pair];
    const float4* w2p = (const float4*)w2s;

    float4 kva[3], kvb[3];
    #pragma unroll
    for (int c = 0; c < 3; ++c) kva[c] = ekq[c * 64];
    #pragma unroll
    for (int c = 0; c < 3; ++c) kvb[c] = ekq[LK + c * 64];

    #pragma unroll
    for (int p = 0; p < 8; ++p) {
        const int ea = 2 * p, eb = 2 * p + 1;
        float4 As[3] = {kva[0], kva[1], kva[2]};
        float4 Bs[3] = {kvb[0], kvb[1], kvb[2]};
        if (p < 7) {
            const float4* np = ekq + (size_t)(ea + 2) * LK;
            kva[0] = np[0]; kva[1] = np[64]; kva[2] = np[128];
            const float4* nq = ekq + (size_t)(eb + 2) * LK;
            kvb[0] = nq[0]; kvb[1] = nq[64]; kvb[2] = nq[128];
        }
        v4f Ea0 = eqp[ea * 4 + 0];
        v4f Ea1 = eqp[ea * 4 + 1];
        v4f Ea2 = eqp[ea * 4 + 2];
        v4f Ea3 = eqp[ea * 4 + 3];
        v4f Eb0 = eqp[eb * 4 + 0];
        v4f Eb1 = eqp[eb * 4 + 1];
        v4f Eb2 = eqp[eb * 4 + 2];
        v4f Eb3 = eqp[eb * 4 + 3];
        float4 wva = w2p[ea], wvb = w2p[eb];
        #pragma unroll
        for (int c = 0; c < 3; ++c) {
            float4 ka = As[c], kb = Bs[c];
            // quad A (e = 4*ea .. 4*ea+3)
            v4f ta0 = fma4(Ea0, sp4(ka.x), sp4(1.f));
            v4f ta1 = fma4(Ea1, sp4(ka.y), sp4(1.f));
            v4f ta2 = fma4(Ea2, sp4(ka.z), sp4(1.f));
            v4f ta3 = fma4(Ea3, sp4(ka.w), sp4(1.f));
            v4f pa12 = ta0 * ta1, pa34 = ta2 * ta3;
            v4f na12 = fma4(sp4(wva.y), ta0, sp4(wva.x) * ta1);
            v4f na34 = fma4(sp4(wva.w), ta2, sp4(wva.z) * ta3);
            v4f numA = fma4(na34, pa12, na12 * pa34);
            v4f denA = pa12 * pa34;
            // quad B (e = 4*eb .. 4*eb+3)
            v4f tb0 = fma4(Eb0, sp4(kb.x), sp4(1.f));
            v4f tb1 = fma4(Eb1, sp4(kb.y), sp4(1.f));
            v4f tb2 = fma4(Eb2, sp4(kb.z), sp4(1.f));
            v4f tb3 = fma4(Eb3, sp4(kb.w), sp4(1.f));
            v4f pb12 = tb0 * tb1, pb34 = tb2 * tb3;
            v4f nb12 = fma4(sp4(wvb.y), tb0, sp4(wvb.x) * tb1);
            v4f nb34 = fma4(sp4(wvb.w), tb2, sp4(wvb.z) * tb3);
            v4f numB = fma4(nb34, pb12, nb12 * pb34);
            v4f denB = pb12 * pb34;
            // merge: numA/denA + numB/denB = (numA*denB + numB*denA) / (denA*denB)
            v4f num = fma4(numB, denA, numA * denB);
            v4f den = denA * denB;
            v4f r;
            r.x = __builtin_amdgcn_rcpf(den.x);
            r.y = __builtin_amdgcn_rcpf(den.y);
            r.z = __builtin_amdgcn_rcpf(den.z);
            r.w = __builtin_amdgcn_rcpf(den.w);
            sc[c] = fma4(num, r, sc[c]);
        }
    }

    // ---- wave-local softmax stats (4 rows) ----
    float s_[3][4];
    float m_[4] = {-3.4e38f, -3.4e38f, -3.4e38f, -3.4e38f};
    #pragma unroll
    for (int c = 0; c < 3; ++c) {
        int kk = hh * 192 + c * 64 + lane;
        bool ok = kk < klen;
        #pragma unroll
        for (int r = 0; r < 4; ++r) {
            s_[c][r] = ok ? -2.0f * sc[c][r] : -3.4e38f;
            m_[r] = fmaxf(m_[r], s_[c][r]);
        }
    }
    #pragma unroll
    for (int off = 32; off >= 1; off >>= 1) {
        #pragma unroll
        for (int r = 0; r < 4; ++r) m_[r] = fmaxf(m_[r], __shfl_xor(m_[r], off));
    }
    float e_[3][4];
    float u_[4] = {0.f, 0.f, 0.f, 0.f};
    #pragma unroll
    for (int c = 0; c < 3; ++c) {
        int kk = hh * 192 + c * 64 + lane;
        bool ok = kk < klen;
        #pragma unroll
        for (int r = 0; r < 4; ++r) {
            e_[c][r] = ok ? __expf(s_[c][r] - m_[r]) : 0.f;
            u_[r] += e_[c][r];
        }
    }
    #pragma unroll
    for (int off = 32; off >= 1; off >>= 1) {
        #pragma unroll
        for (int r = 0; r < 4; ++r) u_[r] += __shfl_xor(u_[r], off);
    }
    if (lane == 0) {
        #pragma unroll
        for (int r = 0; r < 4; ++r) smu[pair][r][hh] = make_float2(m_[r], u_[r]);
    }
    // e_ -> wave-private LDS (same-wave RAW, no barrier)
    {
        float* ar = att_h[wave];
        #pragma unroll
        for (int c = 0; c < 3; ++c)
            #pragma unroll
            for (int r = 0; r < 4; ++r)
                ar[r * 192 + c * 64 + lane] = e_[c][r];
    }

    // ---- PV with UNNORMALIZED e_ weights (normalization deferred past the exchange) ----
    const int kf = lane >> 3, dg = lane & 7;
    const float* vbase = vin + (size_t)b * LK * (NH * 32) + h * 32
                       + (size_t)(hh * 192 + kf) * (NH * 32) + dg * 4;
    const float* ap = att_h[wave];
    float oa[4][4] = {{0.f,0.f,0.f,0.f},{0.f,0.f,0.f,0.f},{0.f,0.f,0.f,0.f},{0.f,0.f,0.f,0.f}};
    float4 vbuf[2];
    vbuf[0] = *(const float4*)(vbase);
    vbuf[1] = *(const float4*)(vbase + (size_t)8 * (NH * 32));
    #pragma unroll
    for (int i = 0; i < 24; ++i) {
        float4 vv = vbuf[i & 1];
        if (i < 22) vbuf[i & 1] = *(const float4*)(vbase + (size_t)((i + 2) * 8) * (NH * 32));
        int k0 = i * 8;
        #pragma unroll
        for (int r = 0; r < 4; ++r) {
            float a = ap[r * 192 + k0 + kf];
            oa[r][0] = __builtin_fmaf(a, vv.x, oa[r][0]);
            oa[r][1] = __builtin_fmaf(a, vv.y, oa[r][1]);
            oa[r][2] = __builtin_fmaf(a, vv.z, oa[r][2]);
            oa[r][3] = __builtin_fmaf(a, vv.w, oa[r][3]);
        }
    }
    #pragma unroll
    for (int r = 0; r < 4; ++r)
        #pragma unroll
        for (int u = 0; u < 4; ++u) {
            oa[r][u] += __shfl_xor(oa[r][u], 8);
            oa[r][u] += __shfl_xor(oa[r][u], 16);
            oa[r][u] += __shfl_xor(oa[r][u], 32);
        }
    __syncthreads();   // (2) smu written long ago by all waves; near-free sync

    // ---- normalization factors (cross-half merge), per row ----
    float f_[4];
    #pragma unroll
    for (int r = 0; r < 4; ++r) {
        float2 A = smu[pair][r][0], B = smu[pair][r][1];
        float mm = fmaxf(A.x, B.x);
        float uu = A.y * __expf(A.x - mm) + B.y * __expf(B.x - mm);
        f_[r] = __expf(m_[r] - mm) * __builtin_amdgcn_rcpf(uu);
    }

    if (kf == 0) {   // lanes 0..7: scale reduced partials by this half's factor
        #pragma unroll
        for (int r = 0; r < 4; ++r)
            pvp[pair][hh][r][dg] = make_float4(oa[r][0] * f_[r], oa[r][1] * f_[r],
                                               oa[r][2] * f_[r], oa[r][3] * f_[r]);
    }
    __syncthreads();   // (3)

    // ---- combine PV halves: wave w -> rows 2w, 2w+1; lanes 0..15 ----
    if (lane < 16) {
        int r = wave * 2 + (lane >> 3);
        int dgo = lane & 7;
        int q = q0 + r;
        float4 xa = pvp[r >> 2][0][r & 3][dgo];
        float4 xb = pvp[r >> 2][1][r & 3][dgo];
        float4 o4;
        bool ok = (q < qlen);
        o4.x = ok ? (xa.x + xb.x) : 0.f;
        o4.y = ok ? (xa.y + xb.y) : 0.f;
        o4.z = ok ? (xa.z + xb.z) : 0.f;
        o4.w = ok ? (xa.w + xb.w) : 0.f;
        ((float4*)(outg + ((size_t)(b * LQ + q)) * (NH * 32) + h * 32))[dgo] = o4;
    }

    // ---- att global writes: p = e_ * f (coalesced, from regs) ----
    {
        float* ag = attg + ((size_t)(bh * LQ + q0 + pair * 4)) * LK + hh * 192;
        #pragma unroll
        for (int r = 0; r < 4; ++r) {
            #pragma unroll
            for (int c = 0; c < 3; ++c) ag[c * 64 + lane] = e_[c][r] * f_[r];
            ag += LK;
        }
    }
}

extern "C" void kernel_launch(void* const* d_in, const int* in_sizes, int n_in,
                              void* d_out, int out_size, void* d_ws, size_t ws_size,
                              hipStream_t stream) {
    const float* q    = (const float*)d_in[0];
    const float* k    = (const float*)d_in[1];
    const float* v    = (const float*)d_in[2];
    const int*   qlen = (const int*)d_in[3];
    const int*   klen = (const int*)d_in[4];
    const float* w1   = (const float*)d_in[5];
    const float* b1   = (const float*)d_in[6];
    const float* w2   = (const float*)d_in[7];
    float* out = (float*)d_out;
    float* att = out + (size_t)BS * LQ * NH * 32;   // out: 196608, att: 2359296 floats
    float* ws  = (float*)d_ws;                      // Ek [bh][e4][k][4]: 1.5 MB

    pre_ek_kernel<<<768, 256, 0, stream>>>(k, w1, b1, ws);
    attn_kernel<<<768, 256, 0, stream>>>(q, v, qlen, klen, w1, w2, ws, out, att);
}

// Round 9
// 93.889 us; speedup vs baseline: 1.0786x; 1.0029x over previous
//
#include <hip/hip_runtime.h>

#define NH 8
#define LQ 384
#define LK 384
#define BS 2

typedef float v4f __attribute__((ext_vector_type(4)));
__device__ __forceinline__ v4f fma4(v4f a, v4f b, v4f c) { return __builtin_elementwise_fma(a, b, c); }
__device__ __forceinline__ v4f sp4(float x) { v4f r; r.x = x; r.y = x; r.z = x; r.w = x; return r; }

// ---------------- Kernel 1: Ek = exp(2*(kW+b1)), layout [bh][e4][k][4] ----------------
// grid = 384: bh = bid/24, 16-k tile. 1.5 blocks/CU.
// [r8 ablation: splitting to 768 blocks x 8-k tiles was neutral -- the w1-load prologue
//  dominates each block, so more/smaller blocks just re-pay it. Keep 16-k tiles.]
__global__ __launch_bounds__(256) void pre_ek_kernel(
    const float* __restrict__ kin, const float* __restrict__ w1,
    const float* __restrict__ b1, float* __restrict__ ws)
{
    __shared__ float tile[16][65];
    const int bid = blockIdx.x;
    const int bh = bid / 24, kt = bid % 24;
    const int b = bh >> 3, h = bh & 7;
    const int k0 = kt * 16;
    const int tid = threadIdx.x;
    const int lane = tid & 63, w = tid >> 6;

    float w1c[32];
    const float* w1p = w1 + (size_t)(h * 64 + 32) * 64 + lane;
    #pragma unroll
    for (int d = 0; d < 32; ++d) w1c[d] = w1p[d * 64];
    const float bv = b1[h * 64 + lane];

    #pragma unroll
    for (int s = 0; s < 4; ++s) {
        int kr = w * 4 + s;
        const float* krow = kin + ((size_t)(b * LK + k0 + kr)) * (NH * 32) + h * 32;
        float acc = bv;
        #pragma unroll
        for (int d = 0; d < 32; ++d) acc = __builtin_fmaf(krow[d], w1c[d], acc);
        tile[kr][lane] = __expf(acc + acc);
    }
    __syncthreads();
    {
        int e4 = tid >> 4, k16 = tid & 15;
        float4 o;
        o.x = tile[k16][e4 * 4 + 0];
        o.y = tile[k16][e4 * 4 + 1];
        o.z = tile[k16][e4 * 4 + 2];
        o.w = tile[k16][e4 * 4 + 3];
        ((float4*)ws)[((size_t)(bh * 16 + e4)) * LK + k0 + k16] = o;
    }
}

// ---------------- Kernel 2: quad-row (v4f) score + paired-rcp + deferred-normalization PV ----------------
// grid = 768 (3 blocks/CU): bh = blk/48, q-tile of 8; wave=(pair4, k-half), 4 q-rows per lane.
// Score inner loop merges rcp across e4-quad PAIRS: 8 e-terms share one v_rcp per row.
// [Proven best: 93.74 us. Ablations: 8-row packing (r2, VGPR blowup +10.9), 16-way rcp
//  (r4, +1.8), V-LDS staging (r5, +2.6: warm-L2 regime has no latency to hide), 3-way
//  k-split TLP at 384 thr (r6/r7, launch_bounds crushed VGPR to 48-56 and spilled).]
__global__ __launch_bounds__(256) void attn_kernel(
    const float* __restrict__ qin, const float* __restrict__ vin,
    const int* __restrict__ qlens, const int* __restrict__ klens,
    const float* __restrict__ w1, const float* __restrict__ w2g,
    const float* __restrict__ ws,
    float* __restrict__ outg, float* __restrict__ attg)
{
    __shared__ __align__(16) float eqi_s[2][256];      // [pair4][e*4+row] interleaved Eq
    __shared__ __align__(16) float att_h[4][4 * 192];  // [wave][row*192 + k] wave-private e_
    __shared__ __align__(16) float w2s[64];
    __shared__ float2 smu[2][4][2];                    // [pair4][row][half] (max, sum)
    __shared__ __align__(16) float4 pvp[2][2][4][8];   // [pair4][half][row][dvq]

    const int tid = threadIdx.x, wave = tid >> 6, lane = tid & 63;
    const int pair = wave >> 1, hh = wave & 1;
    const int bh = blockIdx.x / 48, tile = blockIdx.x % 48;
    const int b = bh >> 3, h = bh & 7;
    const int q0 = tile * 8;
    const int klen = klens[b], qlen = qlens[b];

    // ---- Eq: wave w computes rows 2w, 2w+1 (e = lane), interleaved 4-row groups ----
    {
        float w1c[32];
        const float* w1p = w1 + (size_t)h * 64 * 64 + lane;
        #pragma unroll
        for (int d = 0; d < 32; ++d) w1c[d] = w1p[d * 64];
        #pragma unroll
        for (int j = 0; j < 2; ++j) {
            int r = wave * 2 + j;
            const float* qp = qin + ((size_t)(b * LQ + q0 + r)) * (NH * 32) + h * 32;
            float a = 0.f;
            #pragma unroll
            for (int d = 0; d < 32; ++d) a = __builtin_fmaf(qp[d], w1p[d * 64], a);
            eqi_s[r >> 2][lane * 4 + (r & 3)] = __expf(a + a);
        }
        if (wave == 0) w2s[lane] = w2g[h * 64 + lane];
    }
    __syncthreads();   // (1)

    // ---- score: k = hh*192 + c*64 + lane; 4 q-rows per lane; e4 pairs share one rcp ----
    v4f sc[3];
    sc[0] = sp4(0.f); sc[1] = sp4(0.f); sc[2] = sp4(0.f);
    const float4* ekq = (const float4*)ws + ((size_t)bh * 16) * LK + hh * 192 + lane;
    const v4f*   eqp = (const v4f*)eqi_s[pair];
    const float4* w2p = (const float4*)w2s;

    float4 kva[3], kvb[3];
    #pragma unroll
    for (int c = 0; c < 3; ++c) kva[c] = ekq[c * 64];
    #pragma unroll
    for (int c = 0; c < 3; ++c) kvb[c] = ekq[LK + c * 64];

    #pragma unroll
    for (int p = 0; p < 8; ++p) {
        const int ea = 2 * p, eb = 2 * p + 1;
        float4 As[3] = {kva[0], kva[1], kva[2]};
        float4 Bs[3] = {kvb[0], kvb[1], kvb[2]};
        if (p < 7) {
            const float4* np = ekq + (size_t)(ea + 2) * LK;
            kva[0] = np[0]; kva[1] = np[64]; kva[2] = np[128];
            const float4* nq = ekq + (size_t)(eb + 2) * LK;
            kvb[0] = nq[0]; kvb[1] = nq[64]; kvb[2] = nq[128];
        }
        v4f Ea0 = eqp[ea * 4 + 0];
        v4f Ea1 = eqp[ea * 4 + 1];
        v4f Ea2 = eqp[ea * 4 + 2];
        v4f Ea3 = eqp[ea * 4 + 3];
        v4f Eb0 = eqp[eb * 4 + 0];
        v4f Eb1 = eqp[eb * 4 + 1];
        v4f Eb2 = eqp[eb * 4 + 2];
        v4f Eb3 = eqp[eb * 4 + 3];
        float4 wva = w2p[ea], wvb = w2p[eb];
        #pragma unroll
        for (int c = 0; c < 3; ++c) {
            float4 ka = As[c], kb = Bs[c];
            // quad A (e = 4*ea .. 4*ea+3)
            v4f ta0 = fma4(Ea0, sp4(ka.x), sp4(1.f));
            v4f ta1 = fma4(Ea1, sp4(ka.y), sp4(1.f));
            v4f ta2 = fma4(Ea2, sp4(ka.z), sp4(1.f));
            v4f ta3 = fma4(Ea3, sp4(ka.w), sp4(1.f));
            v4f pa12 = ta0 * ta1, pa34 = ta2 * ta3;
            v4f na12 = fma4(sp4(wva.y), ta0, sp4(wva.x) * ta1);
            v4f na34 = fma4(sp4(wva.w), ta2, sp4(wva.z) * ta3);
            v4f numA = fma4(na34, pa12, na12 * pa34);
            v4f denA = pa12 * pa34;
            // quad B (e = 4*eb .. 4*eb+3)
            v4f tb0 = fma4(Eb0, sp4(kb.x), sp4(1.f));
            v4f tb1 = fma4(Eb1, sp4(kb.y), sp4(1.f));
            v4f tb2 = fma4(Eb2, sp4(kb.z), sp4(1.f));
            v4f tb3 = fma4(Eb3, sp4(kb.w), sp4(1.f));
            v4f pb12 = tb0 * tb1, pb34 = tb2 * tb3;
            v4f nb12 = fma4(sp4(wvb.y), tb0, sp4(wvb.x) * tb1);
            v4f nb34 = fma4(sp4(wvb.w), tb2, sp4(wvb.z) * tb3);
            v4f numB = fma4(nb34, pb12, nb12 * pb34);
            v4f denB = pb12 * pb34;
            // merge: numA/denA + numB/denB = (numA*denB + numB*denA) / (denA*denB)
            v4f num = fma4(numB, denA, numA * denB);
            v4f den = denA * denB;
            v4f r;
            r.x = __builtin_amdgcn_rcpf(den.x);
            r.y = __builtin_amdgcn_rcpf(den.y);
            r.z = __builtin_amdgcn_rcpf(den.z);
            r.w = __builtin_amdgcn_rcpf(den.w);
            sc[c] = fma4(num, r, sc[c]);
        }
    }

    // ---- wave-local softmax stats (4 rows) ----
    float s_[3][4];
    float m_[4] = {-3.4e38f, -3.4e38f, -3.4e38f, -3.4e38f};
    #pragma unroll
    for (int c = 0; c < 3; ++c) {
        int kk = hh * 192 + c * 64 + lane;
        bool ok = kk < klen;
        #pragma unroll
        for (int r = 0; r < 4; ++r) {
            s_[c][r] = ok ? -2.0f * sc[c][r] : -3.4e38f;
            m_[r] = fmaxf(m_[r], s_[c][r]);
        }
    }
    #pragma unroll
    for (int off = 32; off >= 1; off >>= 1) {
        #pragma unroll
        for (int r = 0; r < 4; ++r) m_[r] = fmaxf(m_[r], __shfl_xor(m_[r], off));
    }
    float e_[3][4];
    float u_[4] = {0.f, 0.f, 0.f, 0.f};
    #pragma unroll
    for (int c = 0; c < 3; ++c) {
        int kk = hh * 192 + c * 64 + lane;
        bool ok = kk < klen;
        #pragma unroll
        for (int r = 0; r < 4; ++r) {
            e_[c][r] = ok ? __expf(s_[c][r] - m_[r]) : 0.f;
            u_[r] += e_[c][r];
        }
    }
    #pragma unroll
    for (int off = 32; off >= 1; off >>= 1) {
        #pragma unroll
        for (int r = 0; r < 4; ++r) u_[r] += __shfl_xor(u_[r], off);
    }
    if (lane == 0) {
        #pragma unroll
        for (int r = 0; r < 4; ++r) smu[pair][r][hh] = make_float2(m_[r], u_[r]);
    }
    // e_ -> wave-private LDS (same-wave RAW, no barrier)
    {
        float* ar = att_h[wave];
        #pragma unroll
        for (int c = 0; c < 3; ++c)
            #pragma unroll
            for (int r = 0; r < 4; ++r)
                ar[r * 192 + c * 64 + lane] = e_[c][r];
    }

    // ---- PV with UNNORMALIZED e_ weights (normalization deferred past the exchange) ----
    const int kf = lane >> 3, dg = lane & 7;
    const float* vbase = vin + (size_t)b * LK * (NH * 32) + h * 32
                       + (size_t)(hh * 192 + kf) * (NH * 32) + dg * 4;
    const float* ap = att_h[wave];
    float oa[4][4] = {{0.f,0.f,0.f,0.f},{0.f,0.f,0.f,0.f},{0.f,0.f,0.f,0.f},{0.f,0.f,0.f,0.f}};
    float4 vbuf[2];
    vbuf[0] = *(const float4*)(vbase);
    vbuf[1] = *(const float4*)(vbase + (size_t)8 * (NH * 32));
    #pragma unroll
    for (int i = 0; i < 24; ++i) {
        float4 vv = vbuf[i & 1];
        if (i < 22) vbuf[i & 1] = *(const float4*)(vbase + (size_t)((i + 2) * 8) * (NH * 32));
        int k0 = i * 8;
        #pragma unroll
        for (int r = 0; r < 4; ++r) {
            float a = ap[r * 192 + k0 + kf];
            oa[r][0] = __builtin_fmaf(a, vv.x, oa[r][0]);
            oa[r][1] = __builtin_fmaf(a, vv.y, oa[r][1]);
            oa[r][2] = __builtin_fmaf(a, vv.z, oa[r][2]);
            oa[r][3] = __builtin_fmaf(a, vv.w, oa[r][3]);
        }
    }
    #pragma unroll
    for (int r = 0; r < 4; ++r)
        #pragma unroll
        for (int u = 0; u < 4; ++u) {
            oa[r][u] += __shfl_xor(oa[r][u], 8);
            oa[r][u] += __shfl_xor(oa[r][u], 16);
            oa[r][u] += __shfl_xor(oa[r][u], 32);
        }
    __syncthreads();   // (2) smu written long ago by all waves; near-free sync

    // ---- normalization factors (cross-half merge), per row ----
    float f_[4];
    #pragma unroll
    for (int r = 0; r < 4; ++r) {
        float2 A = smu[pair][r][0], B = smu[pair][r][1];
        float mm = fmaxf(A.x, B.x);
        float uu = A.y * __expf(A.x - mm) + B.y * __expf(B.x - mm);
        f_[r] = __expf(m_[r] - mm) * __builtin_amdgcn_rcpf(uu);
    }

    if (kf == 0) {   // lanes 0..7: scale reduced partials by this half's factor
        #pragma unroll
        for (int r = 0; r < 4; ++r)
            pvp[pair][hh][r][dg] = make_float4(oa[r][0] * f_[r], oa[r][1] * f_[r],
                                               oa[r][2] * f_[r], oa[r][3] * f_[r]);
    }
    __syncthreads();   // (3)

    // ---- combine PV halves: wave w -> rows 2w, 2w+1; lanes 0..15 ----
    if (lane < 16) {
        int r = wave * 2 + (lane >> 3);
        int dgo = lane & 7;
        int q = q0 + r;
        float4 xa = pvp[r >> 2][0][r & 3][dgo];
        float4 xb = pvp[r >> 2][1][r & 3][dgo];
        float4 o4;
        bool ok = (q < qlen);
        o4.x = ok ? (xa.x + xb.x) : 0.f;
        o4.y = ok ? (xa.y + xb.y) : 0.f;
        o4.z = ok ? (xa.z + xb.z) : 0.f;
        o4.w = ok ? (xa.w + xb.w) : 0.f;
        ((float4*)(outg + ((size_t)(b * LQ + q)) * (NH * 32) + h * 32))[dgo] = o4;
    }

    // ---- att global writes: p = e_ * f (coalesced, from regs) ----
    {
        float* ag = attg + ((size_t)(bh * LQ + q0 + pair * 4)) * LK + hh * 192;
        #pragma unroll
        for (int r = 0; r < 4; ++r) {
            #pragma unroll
            for (int c = 0; c < 3; ++c) ag[c * 64 + lane] = e_[c][r] * f_[r];
            ag += LK;
        }
    }
}

extern "C" void kernel_launch(void* const* d_in, const int* in_sizes, int n_in,
                              void* d_out, int out_size, void* d_ws, size_t ws_size,
                              hipStream_t stream) {
    const float* q    = (const float*)d_in[0];
    const float* k    = (const float*)d_in[1];
    const float* v    = (const float*)d_in[2];
    const int*   qlen = (const int*)d_in[3];
    const int*   klen = (const int*)d_in[4];
    const float* w1   = (const float*)d_in[5];
    const float* b1   = (const float*)d_in[6];
    const float* w2   = (const float*)d_in[7];
    float* out = (float*)d_out;
    float* att = out + (size_t)BS * LQ * NH * 32;   // out: 196608, att: 2359296 floats
    float* ws  = (float*)d_ws;                      // Ek [bh][e4][k][4]: 1.5 MB

    pre_ek_kernel<<<384, 256, 0, stream>>>(k, w1, b1, ws);
    attn_kernel<<<768, 256, 0, stream>>>(q, v, qlen, klen, w1, w2, ws, out, att);
}